// Round 9
// baseline (757.970 us; speedup 1.0000x reference)
//
#include <hip/hip_runtime.h>

// CoAttention: B=64, H=768, T=384. out (64,384,2304) fp32.
// ws layout (bytes), aliasing (Qhi/Qlo dead after gemm2 -> AQt/ADt):
//   Qhi bf16 (64,384,768)  @ 0           37,748,736   later: AQt bf16 (64,384,384) @ 0
//   Qlo bf16 (64,384,768)  @ 37748736    37,748,736   later: ADt bf16 (64,384,384) @ 37748736
//   M4  bf16 (64,1536,384) @ 75497472    75,497,472   rows 0..767 Qact^T, 768..1535 C_Q
//   Dt  bf16 (64,768,384)  @ 150994944   37,748,736
//   L   f32  (64,384,384)  @ 188743680   37,748,736   (first 2.36MB = Whi/Wlo scratch,
//                                                      dead once gemm2 writes L)
// R9: selective swizzle. R8 measured: XCD swizzle on gemm1 CUT FETCH 3x but SLOWED
// it 198->250 (latency-bound loop lost the duplicate-stream prefetch effect);
// swizzle on gemm2/3/4 was worth ~-97us combined. So: gemm1 linear grid (R7 form),
// gemm2/3/4 keep the XCD swizzle.

typedef __bf16 bf16x8 __attribute__((ext_vector_type(8)));
typedef __bf16 bf16x4 __attribute__((ext_vector_type(4)));
typedef float  f32x4  __attribute__((ext_vector_type(4)));

#define HH 768
#define TT 384

__device__ inline void split8(const float* __restrict__ p, bf16x8& hi, bf16x8& lo) {
    float4 f0 = *(const float4*)p;
    float4 f1 = *(const float4*)(p + 4);
    float f[8] = {f0.x, f0.y, f0.z, f0.w, f1.x, f1.y, f1.z, f1.w};
#pragma unroll
    for (int i = 0; i < 8; i++) {
        __bf16 h = (__bf16)f[i];
        hi[i] = h;
        lo[i] = (__bf16)(f[i] - (float)h);
    }
}

__device__ inline void split8r(float4 f0, float4 f1, bf16x8& hi, bf16x8& lo) {
    float f[8] = {f0.x, f0.y, f0.z, f0.w, f1.x, f1.y, f1.z, f1.w};
#pragma unroll
    for (int i = 0; i < 8; i++) {
        __bf16 h = (__bf16)f[i];
        hi[i] = h;
        lo[i] = (__bf16)(f[i] - (float)h);
    }
}

// async global->LDS, 16B per lane; LDS side must be wave-uniform base + lane*16
__device__ inline void gload16(const void* g, void* l) {
    __builtin_amdgcn_global_load_lds(
        (const __attribute__((address_space(1))) unsigned int*)g,
        (__attribute__((address_space(3))) unsigned int*)l, 16, 0, 0);
}

// ---- prep: Dt[b][h][s] = bf16(D[b][s][h]);  out[b][s][1536+h] = D[b][s][h] ----
__global__ void prep_kernel(const float* __restrict__ x, __bf16* __restrict__ Dt,
                            float* __restrict__ out) {
    __shared__ float tile[32][33];
    int b = blockIdx.z;
    int h0 = blockIdx.x * 32, s0 = blockIdx.y * 32;
    int tx = threadIdx.x, ty = threadIdx.y;
    const float* src = x + ((size_t)b * HH + TT) * HH;  // D rows
    float* outb = out + (size_t)b * TT * 2304;
#pragma unroll
    for (int j = 0; j < 4; j++) {
        int s = s0 + ty + 8 * j, h = h0 + tx;
        float v = src[(size_t)s * HH + h];
        tile[ty + 8 * j][tx] = v;
        outb[(size_t)s * 2304 + 1536 + h] = v;
    }
    __syncthreads();
    __bf16* Dtb = Dt + (size_t)b * HH * TT;
#pragma unroll
    for (int j = 0; j < 4; j++) {
        int h = h0 + ty + 8 * j, s = s0 + tx;
        Dtb[(size_t)h * TT + s] = (__bf16)tile[tx][ty + 8 * j];
    }
}

// ---- splitW: Whi/Wlo bf16 (768x768 each), stored in L region (dead until gemm2) ----
__global__ void splitW_kernel(const float* __restrict__ W, __bf16* __restrict__ Whi,
                              __bf16* __restrict__ Wlo) {
    int idx = blockIdx.x * 256 + threadIdx.x;  // covers 768*768/8
    bf16x8 h, l;
    split8(W + (size_t)idx * 8, h, l);
    *(bf16x8*)&Whi[(size_t)idx * 8] = h;
    *(bf16x8*)&Wlo[(size_t)idx * 8] = l;
}

// ---- gemm1: Qact = tanh(xQ @ W^T + b), split-precision (3 MFMA), 128x128 tile.
// Pipelined (R7), LINEAR grid (R8 showed XCD swizzle hurts this latency-bound loop). ----
__global__ __launch_bounds__(256) void gemm1_kernel(
    const float* __restrict__ x, const __bf16* __restrict__ Whi,
    const __bf16* __restrict__ Wlo, const float* __restrict__ bias,
    __bf16* __restrict__ Qhi, __bf16* __restrict__ Qlo, __bf16* __restrict__ M4) {
    __shared__ __bf16 Ah[128 * 32], Al[128 * 32];
    __shared__ __bf16 Bh[2][128 * 32], Bl[2][128 * 32];
    const int b = blockIdx.z;
    const int m_blk = blockIdx.y * 128, n_blk = blockIdx.x * 128;
    const int tid = threadIdx.x, lane = tid & 63, wave = tid >> 6;
    const int wm = wave >> 1, wn = wave & 1;
    const int r15 = lane & 15, quad = lane >> 4;
    const float* Abase = x + (size_t)b * HH * HH;  // Q rows
    const int ra0 = tid >> 2, qa = tid & 3;
    const float* aptr0 = Abase + (size_t)(m_blk + ra0) * HH + qa * 8;
    const float* aptr1 = Abase + (size_t)(m_blk + ra0 + 64) * HH + qa * 8;
    f32x4 acc[4][4];
#pragma unroll
    for (int i = 0; i < 4; i++)
#pragma unroll
        for (int j = 0; j < 4; j++) acc[i][j] = (f32x4){0.f, 0.f, 0.f, 0.f};

    // prologue: A(0) into regs, W(0) into B[0]
    float4 a00 = *(const float4*)(aptr0);
    float4 a01 = *(const float4*)(aptr0 + 4);
    float4 a10 = *(const float4*)(aptr1);
    float4 a11 = *(const float4*)(aptr1 + 4);
#pragma unroll
    for (int it = 0; it < 2; it++) {
        int c = it * 256 + tid, r = c >> 2, q = c & 3;
        gload16(Whi + (size_t)(n_blk + r) * HH + q * 8, &Bh[0][c * 8]);
        gload16(Wlo + (size_t)(n_blk + r) * HH + q * 8, &Bl[0][c * 8]);
    }
    int cur = 0;
    for (int k0 = 0; k0 < HH; k0 += 32) {
        {
            bf16x8 h, l;
            split8r(a00, a01, h, l);
            *(bf16x8*)&Ah[tid * 8] = h;
            *(bf16x8*)&Al[tid * 8] = l;
            split8r(a10, a11, h, l);
            *(bf16x8*)&Ah[(256 + tid) * 8] = h;
            *(bf16x8*)&Al[(256 + tid) * 8] = l;
        }
        __syncthreads();  // barrier1
        if (k0 + 32 < HH) {
            a00 = *(const float4*)(aptr0 + k0 + 32);
            a01 = *(const float4*)(aptr0 + k0 + 36);
            a10 = *(const float4*)(aptr1 + k0 + 32);
            a11 = *(const float4*)(aptr1 + k0 + 36);
#pragma unroll
            for (int it = 0; it < 2; it++) {
                int c = it * 256 + tid, r = c >> 2, q = c & 3;
                gload16(Whi + (size_t)(n_blk + r) * HH + k0 + 32 + q * 8, &Bh[cur ^ 1][c * 8]);
                gload16(Wlo + (size_t)(n_blk + r) * HH + k0 + 32 + q * 8, &Bl[cur ^ 1][c * 8]);
            }
        }
        bf16x8 ah[4], al[4], bh[4], bl[4];
#pragma unroll
        for (int i = 0; i < 4; i++) {
            int ra = (wm * 64 + i * 16 + r15) * 32 + quad * 8;
            ah[i] = *(const bf16x8*)&Ah[ra];
            al[i] = *(const bf16x8*)&Al[ra];
            int rb = (wn * 64 + i * 16 + r15) * 32 + quad * 8;
            bh[i] = *(const bf16x8*)&Bh[cur][rb];
            bl[i] = *(const bf16x8*)&Bl[cur][rb];
        }
#pragma unroll
        for (int i = 0; i < 4; i++)
#pragma unroll
            for (int j = 0; j < 4; j++) {
                acc[i][j] = __builtin_amdgcn_mfma_f32_16x16x32_bf16(ah[i], bh[j], acc[i][j], 0, 0, 0);
                acc[i][j] = __builtin_amdgcn_mfma_f32_16x16x32_bf16(ah[i], bl[j], acc[i][j], 0, 0, 0);
                acc[i][j] = __builtin_amdgcn_mfma_f32_16x16x32_bf16(al[i], bh[j], acc[i][j], 0, 0, 0);
            }
        __syncthreads();  // barrier2
        cur ^= 1;
    }
    __bf16* Qh = Qhi + (size_t)b * TT * HH;
    __bf16* Ql = Qlo + (size_t)b * TT * HH;
    __bf16* Mb = M4 + (size_t)b * 1536 * TT;
#pragma unroll
    for (int j = 0; j < 4; j++) {
        int col = n_blk + wn * 64 + j * 16 + r15;  // o
        float bv = bias[col];
#pragma unroll
        for (int i = 0; i < 4; i++) {
            int row0 = m_blk + wm * 64 + i * 16 + quad * 4;  // t
            bf16x4 mrow;
#pragma unroll
            for (int r = 0; r < 4; r++) {
                float v = tanhf(acc[i][j][r] + bv);
                __bf16 qh = (__bf16)v;
                Qh[(size_t)(row0 + r) * HH + col] = qh;
                Ql[(size_t)(row0 + r) * HH + col] = (__bf16)(v - (float)qh);
                mrow[r] = qh;
            }
            *(bf16x4*)&Mb[(size_t)col * TT + row0] = mrow;
        }
    }
}

// ---- gemm2: L[t][s] = sum_h Qact[t][h]*D[s][h], split-precision.
// Pipelined (R7) + XCD swizzle (R8 win): 576 = 8 xcd x 8 x 9; batch on one XCD. ----
__global__ __launch_bounds__(256) void gemm2_kernel(
    const __bf16* __restrict__ Qhi, const __bf16* __restrict__ Qlo,
    const float* __restrict__ x, float* __restrict__ L) {
    __shared__ __bf16 Ah[2][128 * 32], Al[2][128 * 32];
    __shared__ __bf16 Bh[128 * 32], Bl[128 * 32];
    const int id = blockIdx.x;
    const int xcd = id & 7, kk = id >> 3;
    const int inner = kk % 9, b = (kk / 9) * 8 + xcd;
    const int mb = inner / 3, nb = inner % 3;
    const int m_blk = mb * 128, n_blk = nb * 128;
    const int tid = threadIdx.x, lane = tid & 63, wave = tid >> 6;
    const int wm = wave >> 1, wn = wave & 1;
    const int r15 = lane & 15, quad = lane >> 4;
    const __bf16* Qh = Qhi + (size_t)b * TT * HH;
    const __bf16* Ql = Qlo + (size_t)b * TT * HH;
    const float* Dbase = x + ((size_t)b * HH + TT) * HH;  // D rows
    const int rb0 = tid >> 2, qb = tid & 3;
    const float* dptr0 = Dbase + (size_t)(n_blk + rb0) * HH + qb * 8;
    const float* dptr1 = Dbase + (size_t)(n_blk + rb0 + 64) * HH + qb * 8;
    f32x4 acc[4][4];
#pragma unroll
    for (int i = 0; i < 4; i++)
#pragma unroll
        for (int j = 0; j < 4; j++) acc[i][j] = (f32x4){0.f, 0.f, 0.f, 0.f};

    float4 d00 = *(const float4*)(dptr0);
    float4 d01 = *(const float4*)(dptr0 + 4);
    float4 d10 = *(const float4*)(dptr1);
    float4 d11 = *(const float4*)(dptr1 + 4);
#pragma unroll
    for (int it = 0; it < 2; it++) {
        int c = it * 256 + tid, r = c >> 2, q = c & 3;
        gload16(Qh + (size_t)(m_blk + r) * HH + q * 8, &Ah[0][c * 8]);
        gload16(Ql + (size_t)(m_blk + r) * HH + q * 8, &Al[0][c * 8]);
    }
    int cur = 0;
    for (int k0 = 0; k0 < HH; k0 += 32) {
        {
            bf16x8 h, l;
            split8r(d00, d01, h, l);
            *(bf16x8*)&Bh[tid * 8] = h;
            *(bf16x8*)&Bl[tid * 8] = l;
            split8r(d10, d11, h, l);
            *(bf16x8*)&Bh[(256 + tid) * 8] = h;
            *(bf16x8*)&Bl[(256 + tid) * 8] = l;
        }
        __syncthreads();
        if (k0 + 32 < HH) {
            d00 = *(const float4*)(dptr0 + k0 + 32);
            d01 = *(const float4*)(dptr0 + k0 + 36);
            d10 = *(const float4*)(dptr1 + k0 + 32);
            d11 = *(const float4*)(dptr1 + k0 + 36);
#pragma unroll
            for (int it = 0; it < 2; it++) {
                int c = it * 256 + tid, r = c >> 2, q = c & 3;
                gload16(Qh + (size_t)(m_blk + r) * HH + k0 + 32 + q * 8, &Ah[cur ^ 1][c * 8]);
                gload16(Ql + (size_t)(m_blk + r) * HH + k0 + 32 + q * 8, &Al[cur ^ 1][c * 8]);
            }
        }
        bf16x8 ah[4], al[4], bh[4], bl[4];
#pragma unroll
        for (int i = 0; i < 4; i++) {
            int ra = (wm * 64 + i * 16 + r15) * 32 + quad * 8;
            ah[i] = *(const bf16x8*)&Ah[cur][ra];
            al[i] = *(const bf16x8*)&Al[cur][ra];
            int rb = (wn * 64 + i * 16 + r15) * 32 + quad * 8;
            bh[i] = *(const bf16x8*)&Bh[rb];
            bl[i] = *(const bf16x8*)&Bl[rb];
        }
#pragma unroll
        for (int i = 0; i < 4; i++)
#pragma unroll
            for (int j = 0; j < 4; j++) {
                acc[i][j] = __builtin_amdgcn_mfma_f32_16x16x32_bf16(ah[i], bh[j], acc[i][j], 0, 0, 0);
                acc[i][j] = __builtin_amdgcn_mfma_f32_16x16x32_bf16(ah[i], bl[j], acc[i][j], 0, 0, 0);
                acc[i][j] = __builtin_amdgcn_mfma_f32_16x16x32_bf16(al[i], bh[j], acc[i][j], 0, 0, 0);
            }
        __syncthreads();
        cur ^= 1;
    }
    float* Lb = L + (size_t)b * TT * TT;
#pragma unroll
    for (int j = 0; j < 4; j++) {
        int col = n_blk + wn * 64 + j * 16 + r15;  // s
#pragma unroll
        for (int i = 0; i < 4; i++) {
            int row0 = m_blk + wm * 64 + i * 16 + quad * 4;  // t
#pragma unroll
            for (int r = 0; r < 4; r++) Lb[(size_t)(row0 + r) * TT + col] = acc[i][j][r];
        }
    }
}

// ---- softmax over t (column) of L -> AQt[t][s], tiled & coalesced ----
__global__ void softmax_col_kernel(const float* __restrict__ L, __bf16* __restrict__ AQt) {
    int b = blockIdx.y;
    int tx = threadIdx.x, ty = threadIdx.y;
    int s = blockIdx.x * 64 + tx;
    const float* Lb = L + (size_t)b * TT * TT;
    __shared__ float red[4][64];
    float mx = -1e30f;
    for (int t = ty; t < TT; t += 4) mx = fmaxf(mx, Lb[(size_t)t * TT + s]);
    red[ty][tx] = mx;
    __syncthreads();
    mx = fmaxf(fmaxf(red[0][tx], red[1][tx]), fmaxf(red[2][tx], red[3][tx]));
    float sum = 0.f;
    for (int t = ty; t < TT; t += 4) sum += __expf(Lb[(size_t)t * TT + s] - mx);
    __syncthreads();
    red[ty][tx] = sum;
    __syncthreads();
    float inv = 1.0f / (red[0][tx] + red[1][tx] + red[2][tx] + red[3][tx]);
    __bf16* Ab = AQt + (size_t)b * TT * TT;
    for (int t = ty; t < TT; t += 4)
        Ab[(size_t)t * TT + s] = (__bf16)(__expf(Lb[(size_t)t * TT + s] - mx) * inv);
}

// ---- softmax over s (row) of L -> ADt[s][t] (transposed store), tiled & coalesced ----
__global__ void softmax_row_kernel(const float* __restrict__ L, __bf16* __restrict__ ADt) {
    int b = blockIdx.y;
    int t0 = blockIdx.x * 64;
    int tx = threadIdx.x, ty = threadIdx.y;
    int tid = ty * 64 + tx;
    const float* Lb = L + (size_t)b * TT * TT;
    __shared__ __bf16 ex[64][TT];  // 48 KB
    for (int rr = ty; rr < 64; rr += 4) {
        const float* row = Lb + (size_t)(t0 + rr) * TT;
        float v[6];
        float mx = -1e30f;
#pragma unroll
        for (int k = 0; k < 6; k++) {
            v[k] = row[tx + 64 * k];
            mx = fmaxf(mx, v[k]);
        }
#pragma unroll
        for (int off = 32; off > 0; off >>= 1) mx = fmaxf(mx, __shfl_xor(mx, off));
        float sum = 0.f;
#pragma unroll
        for (int k = 0; k < 6; k++) {
            v[k] = __expf(v[k] - mx);
            sum += v[k];
        }
#pragma unroll
        for (int off = 32; off > 0; off >>= 1) sum += __shfl_xor(sum, off);
        float inv = 1.0f / sum;
#pragma unroll
        for (int k = 0; k < 6; k++) ex[rr][tx + 64 * k] = (__bf16)(v[k] * inv);
    }
    __syncthreads();
    __bf16* Ab = ADt + (size_t)b * TT * TT;
    for (int s = tid; s < TT; s += 256) {
#pragma unroll
        for (int j = 0; j < 8; j++) {
            bf16x8 t8;
#pragma unroll
            for (int e = 0; e < 8; e++) t8[e] = ex[j * 8 + e][s];
            *(bf16x8*)&Ab[(size_t)s * TT + t0 + j * 8] = t8;
        }
    }
}

// ---- gemm3: C_Q[h][t] = sum_s Dt[h][s]*AQt[t][s] -> M4 rows 768..1535.
// XCD swizzle (R8 win): 1152 = 8 x 8 x 18; batch on one XCD. ----
__global__ __launch_bounds__(256) void gemm3_kernel(
    const __bf16* __restrict__ Dt, const __bf16* __restrict__ AQt,
    __bf16* __restrict__ M4) {
    __shared__ __bf16 As[128 * 32], Bs[128 * 32];
    const int id = blockIdx.x;
    const int xcd = id & 7, kk = id >> 3;
    const int inner = kk % 18, b = (kk / 18) * 8 + xcd;
    const int nb = inner % 3, mb = inner / 3;  // mb in [0,6)
    const int m_blk = mb * 128, n_blk = nb * 128;
    const int tid = threadIdx.x, lane = tid & 63, wave = tid >> 6;
    const int wm = wave >> 1, wn = wave & 1;
    const int r15 = lane & 15, quad = lane >> 4;
    const __bf16* Ab = Dt + (size_t)b * HH * TT;
    const __bf16* Bb = AQt + (size_t)b * TT * TT;
    f32x4 acc[4][4];
#pragma unroll
    for (int i = 0; i < 4; i++)
#pragma unroll
        for (int j = 0; j < 4; j++) acc[i][j] = (f32x4){0.f, 0.f, 0.f, 0.f};

    for (int k0 = 0; k0 < TT; k0 += 32) {
#pragma unroll
        for (int it = 0; it < 2; it++) {
            int c = it * 256 + tid;
            int r = c >> 2, q = c & 3;
            gload16(Ab + (size_t)(m_blk + r) * TT + k0 + q * 8, &As[c * 8]);
            gload16(Bb + (size_t)(n_blk + r) * TT + k0 + q * 8, &Bs[c * 8]);
        }
        __syncthreads();
        bf16x8 a[4], bf[4];
#pragma unroll
        for (int i = 0; i < 4; i++) {
            a[i] = *(const bf16x8*)&As[(wm * 64 + i * 16 + r15) * 32 + quad * 8];
            bf[i] = *(const bf16x8*)&Bs[(wn * 64 + i * 16 + r15) * 32 + quad * 8];
        }
#pragma unroll
        for (int i = 0; i < 4; i++)
#pragma unroll
            for (int j = 0; j < 4; j++)
                acc[i][j] = __builtin_amdgcn_mfma_f32_16x16x32_bf16(a[i], bf[j], acc[i][j], 0, 0, 0);
        __syncthreads();
    }
    __bf16* Mb = M4 + (size_t)b * 1536 * TT;
#pragma unroll
    for (int j = 0; j < 4; j++) {
        int col = n_blk + wn * 64 + j * 16 + r15;  // t
#pragma unroll
        for (int i = 0; i < 4; i++) {
            int row0 = m_blk + wm * 64 + i * 16 + quad * 4;  // h
#pragma unroll
            for (int r = 0; r < 4; r++)
                Mb[(size_t)(768 + row0 + r) * TT + col] = (__bf16)acc[i][j][r];
        }
    }
}

// ---- gemm4: out[s][i] = sum_t ADt[s][t]*M4[i][t], i<1536.
// XCD swizzle (R8 win): 2304 = 8 x 8 x 36; batch on one XCD. ----
__global__ __launch_bounds__(256) void gemm4_kernel(
    const __bf16* __restrict__ ADt, const __bf16* __restrict__ M4,
    float* __restrict__ out) {
    __shared__ __bf16 As[128 * 32], Bs[128 * 32];
    const int id = blockIdx.x;
    const int xcd = id & 7, kk = id >> 3;
    const int inner = kk % 36, b = (kk / 36) * 8 + xcd;
    const int nb = inner % 12, mb = inner / 12;  // mb in [0,3)
    const int m_blk = mb * 128, n_blk = nb * 128;
    const int tid = threadIdx.x, lane = tid & 63, wave = tid >> 6;
    const int wm = wave >> 1, wn = wave & 1;
    const int r15 = lane & 15, quad = lane >> 4;
    const __bf16* Ab = ADt + (size_t)b * TT * TT;
    const __bf16* Bb = M4 + (size_t)b * 1536 * TT;
    f32x4 acc[4][4];
#pragma unroll
    for (int i = 0; i < 4; i++)
#pragma unroll
        for (int j = 0; j < 4; j++) acc[i][j] = (f32x4){0.f, 0.f, 0.f, 0.f};

    for (int k0 = 0; k0 < TT; k0 += 32) {
#pragma unroll
        for (int it = 0; it < 2; it++) {
            int c = it * 256 + tid;
            int r = c >> 2, q = c & 3;
            gload16(Ab + (size_t)(m_blk + r) * TT + k0 + q * 8, &As[c * 8]);
            gload16(Bb + (size_t)(n_blk + r) * TT + k0 + q * 8, &Bs[c * 8]);
        }
        __syncthreads();
        bf16x8 a[4], bf[4];
#pragma unroll
        for (int i = 0; i < 4; i++) {
            a[i] = *(const bf16x8*)&As[(wm * 64 + i * 16 + r15) * 32 + quad * 8];
            bf[i] = *(const bf16x8*)&Bs[(wn * 64 + i * 16 + r15) * 32 + quad * 8];
        }
#pragma unroll
        for (int i = 0; i < 4; i++)
#pragma unroll
            for (int j = 0; j < 4; j++)
                acc[i][j] = __builtin_amdgcn_mfma_f32_16x16x32_bf16(a[i], bf[j], acc[i][j], 0, 0, 0);
        __syncthreads();
    }
    float* outb = out + (size_t)b * TT * 2304;
#pragma unroll
    for (int j = 0; j < 4; j++) {
        int col = n_blk + wn * 64 + j * 16 + r15;  // i
#pragma unroll
        for (int i = 0; i < 4; i++) {
            int row0 = m_blk + wm * 64 + i * 16 + quad * 4;  // s
#pragma unroll
            for (int r = 0; r < 4; r++)
                outb[(size_t)(row0 + r) * 2304 + col] = acc[i][j][r];
        }
    }
}

extern "C" void kernel_launch(void* const* d_in, const int* in_sizes, int n_in,
                              void* d_out, int out_size, void* d_ws, size_t ws_size,
                              hipStream_t stream) {
    const float* x = (const float*)d_in[0];
    const float* W = (const float*)d_in[1];
    const float* bias = (const float*)d_in[2];
    float* out = (float*)d_out;
    char* ws = (char*)d_ws;

    __bf16* Qhi = (__bf16*)(ws + 0);
    __bf16* Qlo = (__bf16*)(ws + 37748736);
    __bf16* M4 = (__bf16*)(ws + 75497472);
    __bf16* Dt = (__bf16*)(ws + 150994944);
    float* L = (float*)(ws + 188743680);
    // aliases (Qhi/Qlo dead after gemm2):
    __bf16* AQt = (__bf16*)(ws + 0);
    __bf16* ADt = (__bf16*)(ws + 37748736);
    // W split lives in the L region (L not written until gemm2; gemm1 reads W before)
    __bf16* Whi = (__bf16*)(ws + 188743680);
    __bf16* Wlo = Whi + 768 * 768;

    prep_kernel<<<dim3(24, 12, 64), dim3(32, 8), 0, stream>>>(x, Dt, out);
    splitW_kernel<<<288, 256, 0, stream>>>(W, Whi, Wlo);
    gemm1_kernel<<<dim3(6, 3, 64), 256, 0, stream>>>(x, Whi, Wlo, bias, Qhi, Qlo, M4);
    gemm2_kernel<<<576, 256, 0, stream>>>(Qhi, Qlo, x, L);
    softmax_col_kernel<<<dim3(6, 64), dim3(64, 4), 0, stream>>>(L, AQt);
    softmax_row_kernel<<<dim3(6, 64), dim3(64, 4), 0, stream>>>(L, ADt);
    gemm3_kernel<<<1152, 256, 0, stream>>>(Dt, AQt, M4);
    gemm4_kernel<<<2304, 256, 0, stream>>>(ADt, M4, out);
}

// Round 10
// 716.132 us; speedup vs baseline: 1.0584x; 1.0584x over previous
//
#include <hip/hip_runtime.h>

// CoAttention: B=64, H=768, T=384. out (64,384,2304) fp32.
// ws layout (bytes), aliasing (Qhi/Qlo dead after gemm2 -> AQt/ADt):
//   Qhi bf16 (64,384,768)  @ 0           37,748,736   later: AQt bf16 (64,384,384) @ 0
//   Qlo bf16 (64,384,768)  @ 37748736    37,748,736   later: ADt bf16 (64,384,384) @ 37748736
//   M4  bf16 (64,1536,384) @ 75497472    75,497,472   rows 0..767 Qact^T, 768..1535 C_Q
//   Dt  bf16 (64,768,384)  @ 150994944   37,748,736
//   L   f32  (64,384,384)  @ 188743680   37,748,736   (first 2.36MB = Whi/Wlo scratch,
//                                                      dead once gemm2 writes L)
// R10: grid-union of independent kernels. gemm1+prep share no data -> one launch
// (blocks <1152 gemm1, rest prep; LDS overlaid in 48KB buffer so prep co-resides
// in gemm1's latency bubbles). softmax col+row -> one launch (both read L only).
// gemm1 body = R9 linear form (198us); gemm2/3/4 keep R8 XCD swizzle.

typedef __bf16 bf16x8 __attribute__((ext_vector_type(8)));
typedef __bf16 bf16x4 __attribute__((ext_vector_type(4)));
typedef float  f32x4  __attribute__((ext_vector_type(4)));

#define HH 768
#define TT 384

__device__ inline void split8(const float* __restrict__ p, bf16x8& hi, bf16x8& lo) {
    float4 f0 = *(const float4*)p;
    float4 f1 = *(const float4*)(p + 4);
    float f[8] = {f0.x, f0.y, f0.z, f0.w, f1.x, f1.y, f1.z, f1.w};
#pragma unroll
    for (int i = 0; i < 8; i++) {
        __bf16 h = (__bf16)f[i];
        hi[i] = h;
        lo[i] = (__bf16)(f[i] - (float)h);
    }
}

__device__ inline void split8r(float4 f0, float4 f1, bf16x8& hi, bf16x8& lo) {
    float f[8] = {f0.x, f0.y, f0.z, f0.w, f1.x, f1.y, f1.z, f1.w};
#pragma unroll
    for (int i = 0; i < 8; i++) {
        __bf16 h = (__bf16)f[i];
        hi[i] = h;
        lo[i] = (__bf16)(f[i] - (float)h);
    }
}

// async global->LDS, 16B per lane; LDS side must be wave-uniform base + lane*16
__device__ inline void gload16(const void* g, void* l) {
    __builtin_amdgcn_global_load_lds(
        (const __attribute__((address_space(1))) unsigned int*)g,
        (__attribute__((address_space(3))) unsigned int*)l, 16, 0, 0);
}

// ---- splitW: Whi/Wlo bf16 (768x768 each), stored in L region (dead until gemm2) ----
__global__ void splitW_kernel(const float* __restrict__ W, __bf16* __restrict__ Whi,
                              __bf16* __restrict__ Wlo) {
    int idx = blockIdx.x * 256 + threadIdx.x;  // covers 768*768/8
    bf16x8 h, l;
    split8(W + (size_t)idx * 8, h, l);
    *(bf16x8*)&Whi[(size_t)idx * 8] = h;
    *(bf16x8*)&Wlo[(size_t)idx * 8] = l;
}

// ---- fused gemm1 + prep: blocks 0..1151 gemm1 (R9 body), 1152..19583 prep ----
// gemm1: Qact = tanh(xQ@W^T+b), split-precision, 128x128 tile, R7 pipeline, linear grid.
// prep:  Dt[b][h][s] = bf16(D[b][s][h]);  out[b][s][1536+h] = D[b][s][h].
__global__ __launch_bounds__(256) void fused_g1prep_kernel(
    const float* __restrict__ x, const __bf16* __restrict__ Whi,
    const __bf16* __restrict__ Wlo, const float* __restrict__ bias,
    __bf16* __restrict__ Qhi, __bf16* __restrict__ Qlo, __bf16* __restrict__ M4,
    __bf16* __restrict__ Dt, float* __restrict__ out) {
    __shared__ __align__(16) char smem[49152];
    const int tid = threadIdx.x;
    if (blockIdx.x >= 1152) {  // ---------- prep path ----------
        float (*tile)[33] = (float(*)[33])smem;  // 4224 B
        int pid = blockIdx.x - 1152;             // grid was (24,12,64)
        int hb = pid % 24, sb = (pid / 24) % 12, b = pid / 288;
        int h0 = hb * 32, s0 = sb * 32;
        int tx = tid & 31, ty = tid >> 5;
        const float* src = x + ((size_t)b * HH + TT) * HH;  // D rows
        float* outb = out + (size_t)b * TT * 2304;
#pragma unroll
        for (int j = 0; j < 4; j++) {
            int s = s0 + ty + 8 * j, h = h0 + tx;
            float v = src[(size_t)s * HH + h];
            tile[ty + 8 * j][tx] = v;
            outb[(size_t)s * 2304 + 1536 + h] = v;
        }
        __syncthreads();
        __bf16* Dtb = Dt + (size_t)b * HH * TT;
#pragma unroll
        for (int j = 0; j < 4; j++) {
            int h = h0 + ty + 8 * j, s = s0 + tx;
            Dtb[(size_t)h * TT + s] = (__bf16)tile[tx][ty + 8 * j];
        }
        return;
    }
    // ---------- gemm1 path ----------
    __bf16* Ah = (__bf16*)smem;              // 8192 B
    __bf16* Al = (__bf16*)(smem + 8192);     // 8192 B
    __bf16* Bh0 = (__bf16*)(smem + 16384);   // [2][4096] bf16 = 16384 B
    __bf16* Bl0 = (__bf16*)(smem + 32768);   // [2][4096]
    const int id = blockIdx.x;               // linear: nb fastest (matches dim3(6,3,64))
    const int nb = id % 6, mb = (id / 6) % 3, b = id / 18;
    const int m_blk = mb * 128, n_blk = nb * 128;
    const int lane = tid & 63, wave = tid >> 6;
    const int wm = wave >> 1, wn = wave & 1;
    const int r15 = lane & 15, quad = lane >> 4;
    const float* Abase = x + (size_t)b * HH * HH;  // Q rows
    const int ra0 = tid >> 2, qa = tid & 3;
    const float* aptr0 = Abase + (size_t)(m_blk + ra0) * HH + qa * 8;
    const float* aptr1 = Abase + (size_t)(m_blk + ra0 + 64) * HH + qa * 8;
    f32x4 acc[4][4];
#pragma unroll
    for (int i = 0; i < 4; i++)
#pragma unroll
        for (int j = 0; j < 4; j++) acc[i][j] = (f32x4){0.f, 0.f, 0.f, 0.f};

    // prologue: A(0) into regs, W(0) into B[0]
    float4 a00 = *(const float4*)(aptr0);
    float4 a01 = *(const float4*)(aptr0 + 4);
    float4 a10 = *(const float4*)(aptr1);
    float4 a11 = *(const float4*)(aptr1 + 4);
#pragma unroll
    for (int it = 0; it < 2; it++) {
        int c = it * 256 + tid, r = c >> 2, q = c & 3;
        gload16(Whi + (size_t)(n_blk + r) * HH + q * 8, Bh0 + c * 8);
        gload16(Wlo + (size_t)(n_blk + r) * HH + q * 8, Bl0 + c * 8);
    }
    int cur = 0;
    for (int k0 = 0; k0 < HH; k0 += 32) {
        {
            bf16x8 h, l;
            split8r(a00, a01, h, l);
            *(bf16x8*)&Ah[tid * 8] = h;
            *(bf16x8*)&Al[tid * 8] = l;
            split8r(a10, a11, h, l);
            *(bf16x8*)&Ah[(256 + tid) * 8] = h;
            *(bf16x8*)&Al[(256 + tid) * 8] = l;
        }
        __syncthreads();  // barrier1
        if (k0 + 32 < HH) {
            a00 = *(const float4*)(aptr0 + k0 + 32);
            a01 = *(const float4*)(aptr0 + k0 + 36);
            a10 = *(const float4*)(aptr1 + k0 + 32);
            a11 = *(const float4*)(aptr1 + k0 + 36);
#pragma unroll
            for (int it = 0; it < 2; it++) {
                int c = it * 256 + tid, r = c >> 2, q = c & 3;
                gload16(Whi + (size_t)(n_blk + r) * HH + k0 + 32 + q * 8,
                        Bh0 + (cur ^ 1) * 4096 + c * 8);
                gload16(Wlo + (size_t)(n_blk + r) * HH + k0 + 32 + q * 8,
                        Bl0 + (cur ^ 1) * 4096 + c * 8);
            }
        }
        bf16x8 ah[4], al[4], bh[4], bl[4];
#pragma unroll
        for (int i = 0; i < 4; i++) {
            int ra = (wm * 64 + i * 16 + r15) * 32 + quad * 8;
            ah[i] = *(const bf16x8*)&Ah[ra];
            al[i] = *(const bf16x8*)&Al[ra];
            int rb = (wn * 64 + i * 16 + r15) * 32 + quad * 8;
            bh[i] = *(const bf16x8*)&Bh0[cur * 4096 + rb];
            bl[i] = *(const bf16x8*)&Bl0[cur * 4096 + rb];
        }
#pragma unroll
        for (int i = 0; i < 4; i++)
#pragma unroll
            for (int j = 0; j < 4; j++) {
                acc[i][j] = __builtin_amdgcn_mfma_f32_16x16x32_bf16(ah[i], bh[j], acc[i][j], 0, 0, 0);
                acc[i][j] = __builtin_amdgcn_mfma_f32_16x16x32_bf16(ah[i], bl[j], acc[i][j], 0, 0, 0);
                acc[i][j] = __builtin_amdgcn_mfma_f32_16x16x32_bf16(al[i], bh[j], acc[i][j], 0, 0, 0);
            }
        __syncthreads();  // barrier2
        cur ^= 1;
    }
    __bf16* Qh = Qhi + (size_t)b * TT * HH;
    __bf16* Ql = Qlo + (size_t)b * TT * HH;
    __bf16* Mb = M4 + (size_t)b * 1536 * TT;
#pragma unroll
    for (int j = 0; j < 4; j++) {
        int col = n_blk + wn * 64 + j * 16 + r15;  // o
        float bv = bias[col];
#pragma unroll
        for (int i = 0; i < 4; i++) {
            int row0 = m_blk + wm * 64 + i * 16 + quad * 4;  // t
            bf16x4 mrow;
#pragma unroll
            for (int r = 0; r < 4; r++) {
                float v = tanhf(acc[i][j][r] + bv);
                __bf16 qh = (__bf16)v;
                Qh[(size_t)(row0 + r) * HH + col] = qh;
                Ql[(size_t)(row0 + r) * HH + col] = (__bf16)(v - (float)qh);
                mrow[r] = qh;
            }
            *(bf16x4*)&Mb[(size_t)col * TT + row0] = mrow;
        }
    }
}

// ---- gemm2: L[t][s] = sum_h Qact[t][h]*D[s][h], split-precision.
// Pipelined (R7) + XCD swizzle (R8 win): 576 = 8 xcd x 8 x 9; batch on one XCD. ----
__global__ __launch_bounds__(256) void gemm2_kernel(
    const __bf16* __restrict__ Qhi, const __bf16* __restrict__ Qlo,
    const float* __restrict__ x, float* __restrict__ L) {
    __shared__ __bf16 Ah[2][128 * 32], Al[2][128 * 32];
    __shared__ __bf16 Bh[128 * 32], Bl[128 * 32];
    const int id = blockIdx.x;
    const int xcd = id & 7, kk = id >> 3;
    const int inner = kk % 9, b = (kk / 9) * 8 + xcd;
    const int mb = inner / 3, nb = inner % 3;
    const int m_blk = mb * 128, n_blk = nb * 128;
    const int tid = threadIdx.x, lane = tid & 63, wave = tid >> 6;
    const int wm = wave >> 1, wn = wave & 1;
    const int r15 = lane & 15, quad = lane >> 4;
    const __bf16* Qh = Qhi + (size_t)b * TT * HH;
    const __bf16* Ql = Qlo + (size_t)b * TT * HH;
    const float* Dbase = x + ((size_t)b * HH + TT) * HH;  // D rows
    const int rb0 = tid >> 2, qb = tid & 3;
    const float* dptr0 = Dbase + (size_t)(n_blk + rb0) * HH + qb * 8;
    const float* dptr1 = Dbase + (size_t)(n_blk + rb0 + 64) * HH + qb * 8;
    f32x4 acc[4][4];
#pragma unroll
    for (int i = 0; i < 4; i++)
#pragma unroll
        for (int j = 0; j < 4; j++) acc[i][j] = (f32x4){0.f, 0.f, 0.f, 0.f};

    float4 d00 = *(const float4*)(dptr0);
    float4 d01 = *(const float4*)(dptr0 + 4);
    float4 d10 = *(const float4*)(dptr1);
    float4 d11 = *(const float4*)(dptr1 + 4);
#pragma unroll
    for (int it = 0; it < 2; it++) {
        int c = it * 256 + tid, r = c >> 2, q = c & 3;
        gload16(Qh + (size_t)(m_blk + r) * HH + q * 8, &Ah[0][c * 8]);
        gload16(Ql + (size_t)(m_blk + r) * HH + q * 8, &Al[0][c * 8]);
    }
    int cur = 0;
    for (int k0 = 0; k0 < HH; k0 += 32) {
        {
            bf16x8 h, l;
            split8r(d00, d01, h, l);
            *(bf16x8*)&Bh[tid * 8] = h;
            *(bf16x8*)&Bl[tid * 8] = l;
            split8r(d10, d11, h, l);
            *(bf16x8*)&Bh[(256 + tid) * 8] = h;
            *(bf16x8*)&Bl[(256 + tid) * 8] = l;
        }
        __syncthreads();
        if (k0 + 32 < HH) {
            d00 = *(const float4*)(dptr0 + k0 + 32);
            d01 = *(const float4*)(dptr0 + k0 + 36);
            d10 = *(const float4*)(dptr1 + k0 + 32);
            d11 = *(const float4*)(dptr1 + k0 + 36);
#pragma unroll
            for (int it = 0; it < 2; it++) {
                int c = it * 256 + tid, r = c >> 2, q = c & 3;
                gload16(Qh + (size_t)(m_blk + r) * HH + k0 + 32 + q * 8, &Ah[cur ^ 1][c * 8]);
                gload16(Ql + (size_t)(m_blk + r) * HH + k0 + 32 + q * 8, &Al[cur ^ 1][c * 8]);
            }
        }
        bf16x8 ah[4], al[4], bh[4], bl[4];
#pragma unroll
        for (int i = 0; i < 4; i++) {
            int ra = (wm * 64 + i * 16 + r15) * 32 + quad * 8;
            ah[i] = *(const bf16x8*)&Ah[cur][ra];
            al[i] = *(const bf16x8*)&Al[cur][ra];
            int rb = (wn * 64 + i * 16 + r15) * 32 + quad * 8;
            bh[i] = *(const bf16x8*)&Bh[rb];
            bl[i] = *(const bf16x8*)&Bl[rb];
        }
#pragma unroll
        for (int i = 0; i < 4; i++)
#pragma unroll
            for (int j = 0; j < 4; j++) {
                acc[i][j] = __builtin_amdgcn_mfma_f32_16x16x32_bf16(ah[i], bh[j], acc[i][j], 0, 0, 0);
                acc[i][j] = __builtin_amdgcn_mfma_f32_16x16x32_bf16(ah[i], bl[j], acc[i][j], 0, 0, 0);
                acc[i][j] = __builtin_amdgcn_mfma_f32_16x16x32_bf16(al[i], bh[j], acc[i][j], 0, 0, 0);
            }
        __syncthreads();
        cur ^= 1;
    }
    float* Lb = L + (size_t)b * TT * TT;
#pragma unroll
    for (int j = 0; j < 4; j++) {
        int col = n_blk + wn * 64 + j * 16 + r15;  // s
#pragma unroll
        for (int i = 0; i < 4; i++) {
            int row0 = m_blk + wm * 64 + i * 16 + quad * 4;  // t
#pragma unroll
            for (int r = 0; r < 4; r++) Lb[(size_t)(row0 + r) * TT + col] = acc[i][j][r];
        }
    }
}

// ---- fused softmax: bx<6 -> col path (AQt), bx>=6 -> row path (ADt) ----
__global__ void sm_fused_kernel(const float* __restrict__ L, __bf16* __restrict__ AQt,
                                __bf16* __restrict__ ADt) {
    __shared__ __align__(16) char smem[49152];
    int b = blockIdx.y;
    int tx = threadIdx.x, ty = threadIdx.y;
    const float* Lb = L + (size_t)b * TT * TT;
    if (blockIdx.x < 6) {  // ---- col softmax over t -> AQt[t][s] ----
        float (*red)[64] = (float(*)[64])smem;
        int s = blockIdx.x * 64 + tx;
        float mx = -1e30f;
        for (int t = ty; t < TT; t += 4) mx = fmaxf(mx, Lb[(size_t)t * TT + s]);
        red[ty][tx] = mx;
        __syncthreads();
        mx = fmaxf(fmaxf(red[0][tx], red[1][tx]), fmaxf(red[2][tx], red[3][tx]));
        float sum = 0.f;
        for (int t = ty; t < TT; t += 4) sum += __expf(Lb[(size_t)t * TT + s] - mx);
        __syncthreads();
        red[ty][tx] = sum;
        __syncthreads();
        float inv = 1.0f / (red[0][tx] + red[1][tx] + red[2][tx] + red[3][tx]);
        __bf16* Ab = AQt + (size_t)b * TT * TT;
        for (int t = ty; t < TT; t += 4)
            Ab[(size_t)t * TT + s] = (__bf16)(__expf(Lb[(size_t)t * TT + s] - mx) * inv);
    } else {  // ---- row softmax over s -> ADt[s][t] (transposed store) ----
        __bf16 (*ex)[TT] = (__bf16(*)[TT])smem;  // 48 KB
        int t0 = (blockIdx.x - 6) * 64;
        int tid = ty * 64 + tx;
        for (int rr = ty; rr < 64; rr += 4) {
            const float* row = Lb + (size_t)(t0 + rr) * TT;
            float v[6];
            float mx = -1e30f;
#pragma unroll
            for (int k = 0; k < 6; k++) {
                v[k] = row[tx + 64 * k];
                mx = fmaxf(mx, v[k]);
            }
#pragma unroll
            for (int off = 32; off > 0; off >>= 1) mx = fmaxf(mx, __shfl_xor(mx, off));
            float sum = 0.f;
#pragma unroll
            for (int k = 0; k < 6; k++) {
                v[k] = __expf(v[k] - mx);
                sum += v[k];
            }
#pragma unroll
            for (int off = 32; off > 0; off >>= 1) sum += __shfl_xor(sum, off);
            float inv = 1.0f / sum;
#pragma unroll
            for (int k = 0; k < 6; k++) ex[rr][tx + 64 * k] = (__bf16)(v[k] * inv);
        }
        __syncthreads();
        __bf16* Ab = ADt + (size_t)b * TT * TT;
        for (int s = tid; s < TT; s += 256) {
#pragma unroll
            for (int j = 0; j < 8; j++) {
                bf16x8 t8;
#pragma unroll
                for (int e = 0; e < 8; e++) t8[e] = ex[j * 8 + e][s];
                *(bf16x8*)&Ab[(size_t)s * TT + t0 + j * 8] = t8;
            }
        }
    }
}

// ---- gemm3: C_Q[h][t] = sum_s Dt[h][s]*AQt[t][s] -> M4 rows 768..1535.
// XCD swizzle (R8 win): 1152 = 8 x 8 x 18; batch on one XCD. ----
__global__ __launch_bounds__(256) void gemm3_kernel(
    const __bf16* __restrict__ Dt, const __bf16* __restrict__ AQt,
    __bf16* __restrict__ M4) {
    __shared__ __bf16 As[128 * 32], Bs[128 * 32];
    const int id = blockIdx.x;
    const int xcd = id & 7, kk = id >> 3;
    const int inner = kk % 18, b = (kk / 18) * 8 + xcd;
    const int nb = inner % 3, mb = inner / 3;  // mb in [0,6)
    const int m_blk = mb * 128, n_blk = nb * 128;
    const int tid = threadIdx.x, lane = tid & 63, wave = tid >> 6;
    const int wm = wave >> 1, wn = wave & 1;
    const int r15 = lane & 15, quad = lane >> 4;
    const __bf16* Ab = Dt + (size_t)b * HH * TT;
    const __bf16* Bb = AQt + (size_t)b * TT * TT;
    f32x4 acc[4][4];
#pragma unroll
    for (int i = 0; i < 4; i++)
#pragma unroll
        for (int j = 0; j < 4; j++) acc[i][j] = (f32x4){0.f, 0.f, 0.f, 0.f};

    for (int k0 = 0; k0 < TT; k0 += 32) {
#pragma unroll
        for (int it = 0; it < 2; it++) {
            int c = it * 256 + tid;
            int r = c >> 2, q = c & 3;
            gload16(Ab + (size_t)(m_blk + r) * TT + k0 + q * 8, &As[c * 8]);
            gload16(Bb + (size_t)(n_blk + r) * TT + k0 + q * 8, &Bs[c * 8]);
        }
        __syncthreads();
        bf16x8 a[4], bf[4];
#pragma unroll
        for (int i = 0; i < 4; i++) {
            a[i] = *(const bf16x8*)&As[(wm * 64 + i * 16 + r15) * 32 + quad * 8];
            bf[i] = *(const bf16x8*)&Bs[(wn * 64 + i * 16 + r15) * 32 + quad * 8];
        }
#pragma unroll
        for (int i = 0; i < 4; i++)
#pragma unroll
            for (int j = 0; j < 4; j++)
                acc[i][j] = __builtin_amdgcn_mfma_f32_16x16x32_bf16(a[i], bf[j], acc[i][j], 0, 0, 0);
        __syncthreads();
    }
    __bf16* Mb = M4 + (size_t)b * 1536 * TT;
#pragma unroll
    for (int j = 0; j < 4; j++) {
        int col = n_blk + wn * 64 + j * 16 + r15;  // t
#pragma unroll
        for (int i = 0; i < 4; i++) {
            int row0 = m_blk + wm * 64 + i * 16 + quad * 4;  // h
#pragma unroll
            for (int r = 0; r < 4; r++)
                Mb[(size_t)(768 + row0 + r) * TT + col] = (__bf16)acc[i][j][r];
        }
    }
}

// ---- gemm4: out[s][i] = sum_t ADt[s][t]*M4[i][t], i<1536.
// XCD swizzle (R8 win): 2304 = 8 x 8 x 36; batch on one XCD. ----
__global__ __launch_bounds__(256) void gemm4_kernel(
    const __bf16* __restrict__ ADt, const __bf16* __restrict__ M4,
    float* __restrict__ out) {
    __shared__ __bf16 As[128 * 32], Bs[128 * 32];
    const int id = blockIdx.x;
    const int xcd = id & 7, kk = id >> 3;
    const int inner = kk % 36, b = (kk / 36) * 8 + xcd;
    const int nb = inner % 12, mb = inner / 12;  // mb in [0,3)
    const int m_blk = mb * 128, n_blk = nb * 128;
    const int tid = threadIdx.x, lane = tid & 63, wave = tid >> 6;
    const int wm = wave >> 1, wn = wave & 1;
    const int r15 = lane & 15, quad = lane >> 4;
    const __bf16* Ab = ADt + (size_t)b * TT * TT;
    const __bf16* Bb = M4 + (size_t)b * 1536 * TT;
    f32x4 acc[4][4];
#pragma unroll
    for (int i = 0; i < 4; i++)
#pragma unroll
        for (int j = 0; j < 4; j++) acc[i][j] = (f32x4){0.f, 0.f, 0.f, 0.f};

    for (int k0 = 0; k0 < TT; k0 += 32) {
#pragma unroll
        for (int it = 0; it < 2; it++) {
            int c = it * 256 + tid;
            int r = c >> 2, q = c & 3;
            gload16(Ab + (size_t)(m_blk + r) * TT + k0 + q * 8, &As[c * 8]);
            gload16(Bb + (size_t)(n_blk + r) * TT + k0 + q * 8, &Bs[c * 8]);
        }
        __syncthreads();
        bf16x8 a[4], bf[4];
#pragma unroll
        for (int i = 0; i < 4; i++) {
            a[i] = *(const bf16x8*)&As[(wm * 64 + i * 16 + r15) * 32 + quad * 8];
            bf[i] = *(const bf16x8*)&Bs[(wn * 64 + i * 16 + r15) * 32 + quad * 8];
        }
#pragma unroll
        for (int i = 0; i < 4; i++)
#pragma unroll
            for (int j = 0; j < 4; j++)
                acc[i][j] = __builtin_amdgcn_mfma_f32_16x16x32_bf16(a[i], bf[j], acc[i][j], 0, 0, 0);
        __syncthreads();
    }
    float* outb = out + (size_t)b * TT * 2304;
#pragma unroll
    for (int j = 0; j < 4; j++) {
        int col = n_blk + wn * 64 + j * 16 + r15;  // i
#pragma unroll
        for (int i = 0; i < 4; i++) {
            int row0 = m_blk + wm * 64 + i * 16 + quad * 4;  // s
#pragma unroll
            for (int r = 0; r < 4; r++)
                outb[(size_t)(row0 + r) * 2304 + col] = acc[i][j][r];
        }
    }
}

extern "C" void kernel_launch(void* const* d_in, const int* in_sizes, int n_in,
                              void* d_out, int out_size, void* d_ws, size_t ws_size,
                              hipStream_t stream) {
    const float* x = (const float*)d_in[0];
    const float* W = (const float*)d_in[1];
    const float* bias = (const float*)d_in[2];
    float* out = (float*)d_out;
    char* ws = (char*)d_ws;

    __bf16* Qhi = (__bf16*)(ws + 0);
    __bf16* Qlo = (__bf16*)(ws + 37748736);
    __bf16* M4 = (__bf16*)(ws + 75497472);
    __bf16* Dt = (__bf16*)(ws + 150994944);
    float* L = (float*)(ws + 188743680);
    // aliases (Qhi/Qlo dead after gemm2):
    __bf16* AQt = (__bf16*)(ws + 0);
    __bf16* ADt = (__bf16*)(ws + 37748736);
    // W split lives in the L region (L not written until gemm2; gemm1 reads W before)
    __bf16* Whi = (__bf16*)(ws + 188743680);
    __bf16* Wlo = Whi + 768 * 768;

    splitW_kernel<<<288, 256, 0, stream>>>(W, Whi, Wlo);
    fused_g1prep_kernel<<<19584, 256, 0, stream>>>(x, Whi, Wlo, bias, Qhi, Qlo, M4, Dt, out);
    gemm2_kernel<<<576, 256, 0, stream>>>(Qhi, Qlo, x, L);
    sm_fused_kernel<<<dim3(12, 64), dim3(64, 4), 0, stream>>>(L, AQt, ADt);
    gemm3_kernel<<<1152, 256, 0, stream>>>(Dt, AQt, M4);
    gemm4_kernel<<<2304, 256, 0, stream>>>(ADt, M4, out);
}